// Round 8
// baseline (188.284 us; speedup 1.0000x reference)
//
#include <hip/hip_runtime.h>
#include <hip/hip_bf16.h>
#include <math.h>

// Problem constants (B,C,H,W) = (2,64,128,128), R=2 -> K=24 neighbors.
#define NNODES 16384            // H*W
#define KE 24

typedef float f32x4 __attribute__((ext_vector_type(4)));
typedef short bf16x8 __attribute__((ext_vector_type(8)));
typedef unsigned u32x4 __attribute__((ext_vector_type(4)));

union fragcast { u32x4 u; bf16x8 b; };

// Exact 3-way truncation split: v == hi + lo + lo2 (all bf16-representable).
static __device__ __forceinline__ void split3(float v, unsigned& uh,
                                              unsigned& ul, unsigned& um) {
    union { float f; unsigned u; } a; a.f = v;
    uh = a.u & 0xFFFF0000u;
    union { unsigned u; float f; } h; h.u = uh;
    float r1 = v - h.f;                      // exact
    union { float f; unsigned u; } b; b.f = r1;
    ul = b.u & 0xFFFF0000u;
    union { unsigned u; float f; } l; l.u = ul;
    float r2 = r1 - l.f;                     // exact, <= 8 sig bits
    union { float f; unsigned u; } c; c.f = r2;
    um = c.u;                                // top 16 bits == exact bf16
}

// pack top halves of two fp32 bit patterns into one u32 (lo16=even, hi16=odd)
static __device__ __forceinline__ unsigned pack_hi16(unsigned even, unsigned odd) {
    return __builtin_amdgcn_perm(odd, even, 0x07060302u);   // v_perm_b32
}

// ---------------------------------------------------------------------------
// A: per-node precompute (absorbs the weight transpose; no aux kernel).
//    Block = 128 threads, one mat x 64h x 128 nodes; thread owns 8h x 8n.
// ---------------------------------------------------------------------------
__global__ __launch_bounds__(128) void precompute_k(
    const float* __restrict__ x, const float* __restrict__ W1,
    const float* __restrict__ Wm, const float* __restrict__ b1,
    const float* __restrict__ bm,
    float* __restrict__ zsrc, float* __restrict__ ztgt, float* __restrict__ msg)
{
    __shared__ float xt[64][128];   // [c][node]  32 KB
    __shared__ float wl[64][64];    // [c][h]     16 KB
    const int t = threadIdx.x;
    const int mat = blockIdx.x >> 8;        // grid = 3*256
    const int tile = blockIdx.x & 255;
    const int n0 = tile * 128;
    const int b = n0 >> 14;
    const int nl0 = n0 & (NNODES - 1);
    const float* xb = x + (size_t)b * 64 * NNODES + nl0;

    #pragma unroll
    for (int r = 0; r < 16; ++r) {
        int idx = r * 128 + t;              // 2048 float4s
        int c = idx >> 5, j4 = idx & 31;
        float4 v = *(const float4*)(xb + (size_t)c * NNODES + j4 * 4);
        *(float4*)&xt[c][j4 * 4] = v;
    }
    // wl[c][h]: linear idx = c*64 + h; LDS write coalesced; global reads are
    // scattered but W1/Wm are 33 KB L1/L2-hot.
    #pragma unroll
    for (int r = 0; r < 32; ++r) {
        int idx = r * 128 + t;
        int c = idx >> 6, h = idx & 63;
        float v = (mat == 0) ? W1[h * 130 + c]
                : (mat == 1) ? W1[h * 130 + 64 + c]
                             : Wm[h * 64 + c];
        (&wl[0][0])[idx] = v;
    }
    __syncthreads();

    const int i = t >> 4;   // h-octet
    const int j = t & 15;   // node-group

    float acc[8][8];
    #pragma unroll
    for (int a = 0; a < 8; ++a)
        #pragma unroll
        for (int bb = 0; bb < 8; ++bb) acc[a][bb] = 0.f;

    #pragma unroll 4
    for (int c = 0; c < 64; ++c) {
        float4 w0 = *(const float4*)&wl[c][i * 8];
        float4 w1 = *(const float4*)&wl[c][i * 8 + 4];
        float4 x0 = *(const float4*)&xt[c][j * 8];
        float4 x1 = *(const float4*)&xt[c][j * 8 + 4];
        float wv[8] = {w0.x, w0.y, w0.z, w0.w, w1.x, w1.y, w1.z, w1.w};
        float xv[8] = {x0.x, x0.y, x0.z, x0.w, x1.x, x1.y, x1.z, x1.w};
        #pragma unroll
        for (int a = 0; a < 8; ++a)
            #pragma unroll
            for (int bb = 0; bb < 8; ++bb)
                acc[a][bb] = fmaf(wv[a], xv[bb], acc[a][bb]);
    }

    #pragma unroll
    for (int a = 0; a < 8; ++a) {
        float bv = (mat == 0) ? b1[i * 8 + a] : (mat == 2) ? bm[i * 8 + a] : 0.f;
        #pragma unroll
        for (int bb = 0; bb < 8; ++bb) {
            float v = acc[a][bb] + bv;
            acc[a][bb] = (mat == 2) ? fmaxf(v, 0.f) : v;
        }
    }

    float* dst = (mat == 0) ? zsrc : (mat == 1) ? ztgt : msg;
    #pragma unroll
    for (int nn = 0; nn < 8; ++nn) {
        float* o = dst + (size_t)(n0 + j * 8 + nn) * 64 + i * 8;
        *(float4*)o       = make_float4(acc[0][nn], acc[1][nn], acc[2][nn], acc[3][nn]);
        *(float4*)(o + 4) = make_float4(acc[4][nn], acc[5][nn], acc[6][nn], acc[7][nn]);
    }
}

// ---------------------------------------------------------------------------
// B: fused scorer + aggregation. Block = 256 threads / 4 waves / 16 nodes.
//    W2 fragments pre-split into LDS (kills the scratch spill); scores stay
//    in LDS; then rank/mask/weights, msg gather, Wo matmul + residual, store.
// ---------------------------------------------------------------------------
__global__ __launch_bounds__(256, 3) void fused_k(
    const float* __restrict__ zsrc, const float* __restrict__ ztgt,
    const float* __restrict__ msg,  const float* __restrict__ x,
    const float* __restrict__ W1,   const float* __restrict__ W2,
    const float* __restrict__ b2,   const float* __restrict__ W3,
    const float* __restrict__ b3,   const float* __restrict__ thrp,
    const float* __restrict__ Wo,   const float* __restrict__ bo,
    float* __restrict__ out)
{
    __shared__ fragcast fraglds[12 * 64];               // 12 KB: slot(split,jt,kt) x lane
    __shared__ __align__(16) float zpos_lds[24 * 68];   // 6.5 KB, padded rows
    __shared__ float sc[16 * 24];                        // scores
    __shared__ float wle[16 * 24];                       // edge weights
    __shared__ float sumw[16];
    __shared__ __align__(16) float aggL[16][64];
    __shared__ float ott[16 * 68];                       // out staging [node][o]

    const int t = threadIdx.x;
    const int l = t & 63;
    const int lcol = l & 15;
    const int lgrp = l >> 4;
    const int w = t >> 6;
    const int blkbase = blockIdx.x * 16;
    const int b = blkbase >> 14;
    const int nl0 = blkbase & (NNODES - 1);

    // ---- phase 0a: zpos table (bit-identical to prior aux_k) ----
    #pragma unroll
    for (int r = 0; r < 6; ++r) {
        int idx = r * 256 + t;              // 1536 entries
        int k = idx >> 6, h = idx & 63;
        int kk = k + (k >= 12 ? 1 : 0);
        int q5 = (kk * 52) >> 8;
        int dy = q5 - 2, dx = kk - 5 * q5 - 2;
        zpos_lds[k * 68 + h] = W1[h * 130 + 128] * (dx * 0.5f)
                             + W1[h * 130 + 129] * (dy * 0.5f);
    }
    // ---- phase 0b: W2 fragments, exact 3-way split, written by wave 0 ----
    if (t < 64) {
        #pragma unroll
        for (int jt = 0; jt < 2; ++jt)
            #pragma unroll
            for (int kt = 0; kt < 2; ++kt) {
                fragcast fh, fl, fl2;
                const float* wr = W2 + (size_t)(jt * 16 + lcol) * 64 + kt * 32 + lgrp * 8;
                #pragma unroll
                for (int d = 0; d < 4; ++d) {
                    unsigned h0, l0, m0, h1, l1, m1;
                    split3(wr[2 * d],     h0, l0, m0);
                    split3(wr[2 * d + 1], h1, l1, m1);
                    fh.u[d]  = pack_hi16(h0, h1);
                    fl.u[d]  = pack_hi16(l0, l1);
                    fl2.u[d] = pack_hi16(m0, m1);
                }
                fraglds[((0 * 2 + jt) * 2 + kt) * 64 + l] = fh;
                fraglds[((1 * 2 + jt) * 2 + kt) * 64 + l] = fl;
                fraglds[((2 * 2 + jt) * 2 + kt) * 64 + l] = fl2;
            }
    }
    __syncthreads();

    // ---- phase 1: scores for this block's 16 nodes (4 per wave) ----
    {
        f32x4 b2l[2], w3l[2];
        b2l[0] = *(const f32x4*)(b2 + lgrp * 4);
        b2l[1] = *(const f32x4*)(b2 + 16 + lgrp * 4);
        w3l[0] = *(const f32x4*)(W3 + lgrp * 4);
        w3l[1] = *(const f32x4*)(W3 + 16 + lgrp * 4);
        const float b3s = b3[0];

        #pragma unroll 1
        for (int p = 0; p < 2; ++p) {
            const int node0 = blkbase + w * 4 + p * 2;

            for (int Mt = 0; Mt < 3; ++Mt) {
                const int ke = Mt * 16 + lcol;       // edge idx within pair
                const int nsel = (ke >= 24) ? 1 : 0;
                const int node = node0 + nsel;
                const int k = ke - 24 * nsel;
                const int nl = node & (NNODES - 1);
                const int yy = nl >> 7, xx = nl & 127;
                const int kk = k + (k >= 12 ? 1 : 0);
                const int q5 = (kk * 52) >> 8;
                const int dy = q5 - 2, dx = kk - 5 * q5 - 2;
                const int ny = min(max(yy + dy, 0), 127);
                const int nx = min(max(xx + dx, 0), 127);
                const int nbn = (b << 14) + (ny << 7) + nx;

                f32x4 ac0A = {0.f,0.f,0.f,0.f}, ac0B = {0.f,0.f,0.f,0.f};
                f32x4 ac1A = {0.f,0.f,0.f,0.f}, ac1B = {0.f,0.f,0.f,0.f};

                #pragma unroll
                for (int kt = 0; kt < 2; ++kt) {
                    const int c0 = kt * 32 + lgrp * 8;
                    float4 a0 = *(const float4*)(zsrc + (size_t)node * 64 + c0);
                    float4 a1 = *(const float4*)(zsrc + (size_t)node * 64 + c0 + 4);
                    float4 t0 = *(const float4*)(ztgt + (size_t)nbn * 64 + c0);
                    float4 t1 = *(const float4*)(ztgt + (size_t)nbn * 64 + c0 + 4);
                    float4 p0 = *(const float4*)&zpos_lds[k * 68 + c0];
                    float4 p1 = *(const float4*)&zpos_lds[k * 68 + c0 + 4];
                    float v[8];
                    v[0] = fmaxf(a0.x + t0.x + p0.x, 0.f);
                    v[1] = fmaxf(a0.y + t0.y + p0.y, 0.f);
                    v[2] = fmaxf(a0.z + t0.z + p0.z, 0.f);
                    v[3] = fmaxf(a0.w + t0.w + p0.w, 0.f);
                    v[4] = fmaxf(a1.x + t1.x + p1.x, 0.f);
                    v[5] = fmaxf(a1.y + t1.y + p1.y, 0.f);
                    v[6] = fmaxf(a1.z + t1.z + p1.z, 0.f);
                    v[7] = fmaxf(a1.w + t1.w + p1.w, 0.f);

                    fragcast Bh, Bl, Bl2;
                    #pragma unroll
                    for (int d = 0; d < 4; ++d) {
                        unsigned h0, l0, m0, h1, l1, m1;
                        split3(v[2 * d],     h0, l0, m0);
                        split3(v[2 * d + 1], h1, l1, m1);
                        Bh.u[d]  = pack_hi16(h0, h1);
                        Bl.u[d]  = pack_hi16(l0, l1);
                        Bl2.u[d] = pack_hi16(m0, m1);
                    }

                    // A fragments from LDS (ds_read_b128 each, per-lane slot)
                    bf16x8 Ah0  = fraglds[((0*2+0)*2+kt)*64 + l].b;
                    bf16x8 Ah1  = fraglds[((0*2+1)*2+kt)*64 + l].b;
                    bf16x8 Al0  = fraglds[((1*2+0)*2+kt)*64 + l].b;
                    bf16x8 Al1  = fraglds[((1*2+1)*2+kt)*64 + l].b;
                    bf16x8 Al20 = fraglds[((2*2+0)*2+kt)*64 + l].b;
                    bf16x8 Al21 = fraglds[((2*2+1)*2+kt)*64 + l].b;

                    ac0A = __builtin_amdgcn_mfma_f32_16x16x32_bf16(Ah0,  Bh.b,  ac0A, 0, 0, 0);
                    ac1A = __builtin_amdgcn_mfma_f32_16x16x32_bf16(Ah1,  Bh.b,  ac1A, 0, 0, 0);
                    ac0B = __builtin_amdgcn_mfma_f32_16x16x32_bf16(Al0,  Bh.b,  ac0B, 0, 0, 0);
                    ac1B = __builtin_amdgcn_mfma_f32_16x16x32_bf16(Al1,  Bh.b,  ac1B, 0, 0, 0);
                    ac0A = __builtin_amdgcn_mfma_f32_16x16x32_bf16(Al20, Bh.b,  ac0A, 0, 0, 0);
                    ac1A = __builtin_amdgcn_mfma_f32_16x16x32_bf16(Al21, Bh.b,  ac1A, 0, 0, 0);
                    ac0B = __builtin_amdgcn_mfma_f32_16x16x32_bf16(Ah0,  Bl.b,  ac0B, 0, 0, 0);
                    ac1B = __builtin_amdgcn_mfma_f32_16x16x32_bf16(Ah1,  Bl.b,  ac1B, 0, 0, 0);
                    ac0A = __builtin_amdgcn_mfma_f32_16x16x32_bf16(Al0,  Bl.b,  ac0A, 0, 0, 0);
                    ac1A = __builtin_amdgcn_mfma_f32_16x16x32_bf16(Al1,  Bl.b,  ac1A, 0, 0, 0);
                    ac0B = __builtin_amdgcn_mfma_f32_16x16x32_bf16(Ah0,  Bl2.b, ac0B, 0, 0, 0);
                    ac1B = __builtin_amdgcn_mfma_f32_16x16x32_bf16(Ah1,  Bl2.b, ac1B, 0, 0, 0);
                }

                const f32x4 s0 = ac0A + ac0B;
                const f32x4 s1 = ac1A + ac1B;
                float sacc = 0.f;
                #pragma unroll
                for (int q = 0; q < 4; ++q) {
                    sacc = fmaf(fmaxf(s0[q] + b2l[0][q], 0.f), w3l[0][q], sacc);
                    sacc = fmaf(fmaxf(s1[q] + b2l[1][q], 0.f), w3l[1][q], sacc);
                }
                sacc += __shfl_xor(sacc, 16);
                sacc += __shfl_xor(sacc, 32);
                float sig = 1.f / (1.f + expf(-(sacc + b3s)));
                if (l < 16) {
                    int keS = Mt * 16 + l;
                    int ns = (keS >= 24) ? 1 : 0;
                    sc[(w * 4 + p * 2 + ns) * 24 + keS - 24 * ns] = sig;
                }
            }
        }
    }
    __syncthreads();

    // ---- phase 2: edge weights (rank/count/threshold, tie-stable) ----
    const float thr_v = 1.f / (1.f + expf(-thrp[0]));
    #pragma unroll
    for (int rep = 0; rep < 2; ++rep) {
        int e = rep * 256 + t;
        if (e < 384) {
            int nl = (int)(((unsigned)(e >> 3) * 171u) >> 9);   // e/24
            int k = e - nl * 24;
            float s_e = sc[e];
            int rank = 0, cnt = 0;
            #pragma unroll
            for (int j = 0; j < 24; ++j) {
                float sj = sc[nl * 24 + j];
                rank += (sj > s_e || (sj == s_e && j < k)) ? 1 : 0;
                cnt  += (sj >= thr_v) ? 1 : 0;
            }
            bool mask = (cnt > 8) ? (rank < 8)
                      : ((cnt < 3) ? (rank < 3) : (s_e >= thr_v));
            float keep = 1.f / (1.f + expf(-(s_e - thr_v) * 10.f));
            wle[e] = mask ? s_e * keep : 0.f;
        }
    }
    __syncthreads();

    if (t < 16) {
        float s = 0.f;
        #pragma unroll
        for (int k = 0; k < 24; ++k) s += wle[t * 24 + k];
        sumw[t] = s + 1e-6f;
    }
    __syncthreads();

    // ---- phase 4: weighted msg gather (rows coalesced 256B) ----
    {
        const int c = t & 63, ng = t >> 6;
        #pragma unroll
        for (int it = 0; it < 4; ++it) {
            int nl = ng + it * 4;
            int nn = nl0 + nl;
            int yy = nn >> 7, xx = nn & 127;
            float acc = 0.f;
            #pragma unroll
            for (int k = 0; k < 24; ++k) {
                int kk = k + (k >= 12 ? 1 : 0);
                int q5 = (kk * 52) >> 8;
                int dy = q5 - 2, dx = kk - 5 * q5 - 2;
                int ny = min(max(yy + dy, 0), 127);
                int nx = min(max(xx + dx, 0), 127);
                int nb = (b << 14) + (ny << 7) + nx;
                acc = fmaf(wle[nl * 24 + k], msg[(size_t)nb * 64 + c], acc);
            }
            aggL[nl][c] = acc / sumw[nl];
        }
    }
    __syncthreads();

    // ---- phase 5: out = x + agg @ Wo.T + bo (Wo read direct, L1-hot) ----
    {
        const int o = t & 63, g4 = t >> 6;
        const float4* wr = (const float4*)(Wo + (size_t)o * 64);
        #pragma unroll
        for (int it = 0; it < 4; ++it) {
            int nl = g4 + it * 4;
            const float4* ar = (const float4*)aggL[nl];
            float a0 = 0.f, a1 = 0.f, a2 = 0.f, a3 = 0.f;
            #pragma unroll
            for (int c4 = 0; c4 < 16; ++c4) {
                float4 wv = wr[c4];
                float4 av = ar[c4];
                a0 = fmaf(av.x, wv.x, a0);
                a1 = fmaf(av.y, wv.y, a1);
                a2 = fmaf(av.z, wv.z, a2);
                a3 = fmaf(av.w, wv.w, a3);
            }
            float v = (a0 + a1) + (a2 + a3) + bo[o]
                    + x[(size_t)b * 64 * NNODES + (size_t)o * NNODES + nl0 + nl];
            ott[nl * 68 + o] = v;
        }
    }
    __syncthreads();

    // ---- phase 6: coalesced stores (64B per o-row per block) ----
    {
        int o = t >> 2, j = t & 3;
        float4 v = make_float4(ott[(4 * j + 0) * 68 + o], ott[(4 * j + 1) * 68 + o],
                               ott[(4 * j + 2) * 68 + o], ott[(4 * j + 3) * 68 + o]);
        *(float4*)(out + (size_t)b * 64 * NNODES + (size_t)o * NNODES + nl0 + 4 * j) = v;
    }
}

// ---------------------------------------------------------------------------
extern "C" void kernel_launch(void* const* d_in, const int* in_sizes, int n_in,
                              void* d_out, int out_size, void* d_ws, size_t ws_size,
                              hipStream_t stream)
{
    const float* x   = (const float*)d_in[0];
    const float* W1  = (const float*)d_in[1];
    const float* b1  = (const float*)d_in[2];
    const float* W2  = (const float*)d_in[3];
    const float* b2  = (const float*)d_in[4];
    const float* W3  = (const float*)d_in[5];
    const float* b3  = (const float*)d_in[6];
    const float* thr = (const float*)d_in[7];
    const float* Wm  = (const float*)d_in[8];
    const float* bm  = (const float*)d_in[9];
    const float* Wo  = (const float*)d_in[10];
    const float* bo  = (const float*)d_in[11];
    float* out = (float*)d_out;
    float* ws  = (float*)d_ws;

    // ws layout (floats): zsrc[2M] ztgt[2M] msg[2M]
    float* zsrc = ws;
    float* ztgt = ws + 2097152;
    float* msg  = ws + 4194304;

    hipLaunchKernelGGL(precompute_k, dim3(768), dim3(128), 0, stream,
                       x, W1, Wm, b1, bm, zsrc, ztgt, msg);
    hipLaunchKernelGGL(fused_k, dim3(2048), dim3(256), 0, stream,
                       zsrc, ztgt, msg, x, W1, W2, b2, W3, b3, thr, Wo, bo, out);
}

// Round 9
// 133.233 us; speedup vs baseline: 1.4132x; 1.4132x over previous
//
#include <hip/hip_runtime.h>
#include <hip/hip_bf16.h>
#include <math.h>

// Problem constants (B,C,H,W) = (2,64,128,128), R=2 -> K=24 neighbors.
#define NNODES 16384            // H*W
#define KE 24

typedef float f32x4 __attribute__((ext_vector_type(4)));
typedef short bf16x8 __attribute__((ext_vector_type(8)));
typedef unsigned u32x4 __attribute__((ext_vector_type(4)));

union fragcast { u32x4 u; bf16x8 b; };

// Exact 3-way truncation split: v == hi + lo + lo2 (all bf16-representable).
static __device__ __forceinline__ void split3(float v, unsigned& uh,
                                              unsigned& ul, unsigned& um) {
    union { float f; unsigned u; } a; a.f = v;
    uh = a.u & 0xFFFF0000u;
    union { unsigned u; float f; } h; h.u = uh;
    float r1 = v - h.f;                      // exact
    union { float f; unsigned u; } b; b.f = r1;
    ul = b.u & 0xFFFF0000u;
    union { unsigned u; float f; } l; l.u = ul;
    float r2 = r1 - l.f;                     // exact, <= 8 sig bits
    union { float f; unsigned u; } c; c.f = r2;
    um = c.u;                                // top 16 bits == exact bf16
}

static __device__ __forceinline__ unsigned pack_hi16(unsigned even, unsigned odd) {
    return __builtin_amdgcn_perm(odd, even, 0x07060302u);   // v_perm_b32
}

// ---------------------------------------------------------------------------
// aux: zpos[k][h] table only (1 block)
// ---------------------------------------------------------------------------
__global__ void aux_k(const float* __restrict__ W1, float* __restrict__ zpos)
{
    int t = threadIdx.x;
    for (int idx = t; idx < KE * 64; idx += 256) {
        int k = idx >> 6, h = idx & 63;
        int kk = k + (k >= 12 ? 1 : 0);       // skip center of 5x5
        int q5 = (kk * 52) >> 8;              // kk/5 for kk<25
        int dy = q5 - 2;
        int dx = kk - 5 * q5 - 2;
        zpos[idx] = W1[h * 130 + 128] * (dx * 0.5f)
                  + W1[h * 130 + 129] * (dy * 0.5f);
    }
}

// ---------------------------------------------------------------------------
// A: per-node precompute (absorbs weight transpose). 128 thr, 8h x 8n tiles.
// ---------------------------------------------------------------------------
__global__ __launch_bounds__(128) void precompute_k(
    const float* __restrict__ x, const float* __restrict__ W1,
    const float* __restrict__ Wm, const float* __restrict__ b1,
    const float* __restrict__ bm,
    float* __restrict__ zsrc, float* __restrict__ ztgt, float* __restrict__ msg)
{
    __shared__ float xt[64][128];   // [c][node]  32 KB
    __shared__ float wl[64][64];    // [c][h]     16 KB
    const int t = threadIdx.x;
    const int mat = blockIdx.x >> 8;        // grid = 3*256
    const int tile = blockIdx.x & 255;
    const int n0 = tile * 128;
    const int b = n0 >> 14;
    const int nl0 = n0 & (NNODES - 1);
    const float* xb = x + (size_t)b * 64 * NNODES + nl0;

    #pragma unroll
    for (int r = 0; r < 16; ++r) {
        int idx = r * 128 + t;
        int c = idx >> 5, j4 = idx & 31;
        float4 v = *(const float4*)(xb + (size_t)c * NNODES + j4 * 4);
        *(float4*)&xt[c][j4 * 4] = v;
    }
    #pragma unroll
    for (int r = 0; r < 32; ++r) {
        int idx = r * 128 + t;
        int c = idx >> 6, h = idx & 63;
        float v = (mat == 0) ? W1[h * 130 + c]
                : (mat == 1) ? W1[h * 130 + 64 + c]
                             : Wm[h * 64 + c];
        (&wl[0][0])[idx] = v;
    }
    __syncthreads();

    const int i = t >> 4;   // h-octet
    const int j = t & 15;   // node-group

    float acc[8][8];
    #pragma unroll
    for (int a = 0; a < 8; ++a)
        #pragma unroll
        for (int bb = 0; bb < 8; ++bb) acc[a][bb] = 0.f;

    #pragma unroll 4
    for (int c = 0; c < 64; ++c) {
        float4 w0 = *(const float4*)&wl[c][i * 8];
        float4 w1 = *(const float4*)&wl[c][i * 8 + 4];
        float4 x0 = *(const float4*)&xt[c][j * 8];
        float4 x1 = *(const float4*)&xt[c][j * 8 + 4];
        float wv[8] = {w0.x, w0.y, w0.z, w0.w, w1.x, w1.y, w1.z, w1.w};
        float xv[8] = {x0.x, x0.y, x0.z, x0.w, x1.x, x1.y, x1.z, x1.w};
        #pragma unroll
        for (int a = 0; a < 8; ++a)
            #pragma unroll
            for (int bb = 0; bb < 8; ++bb)
                acc[a][bb] = fmaf(wv[a], xv[bb], acc[a][bb]);
    }

    #pragma unroll
    for (int a = 0; a < 8; ++a) {
        float bv = (mat == 0) ? b1[i * 8 + a] : (mat == 2) ? bm[i * 8 + a] : 0.f;
        #pragma unroll
        for (int bb = 0; bb < 8; ++bb) {
            float v = acc[a][bb] + bv;
            acc[a][bb] = (mat == 2) ? fmaxf(v, 0.f) : v;
        }
    }

    float* dst = (mat == 0) ? zsrc : (mat == 1) ? ztgt : msg;
    #pragma unroll
    for (int nn = 0; nn < 8; ++nn) {
        float* o = dst + (size_t)(n0 + j * 8 + nn) * 64 + i * 8;
        *(float4*)o       = make_float4(acc[0][nn], acc[1][nn], acc[2][nn], acc[3][nn]);
        *(float4*)(o + 4) = make_float4(acc[4][nn], acc[5][nn], acc[6][nn], acc[7][nn]);
    }
}

// ---------------------------------------------------------------------------
// B: scorer. Exact 3-way-split bf16 MFMA, W2 frags in conflict-free LDS
//    (lane-major stride 13*16B), trip-3 loop (small I-footprint), depth-1
//    software prefetch of the ztgt gather.
// ---------------------------------------------------------------------------
struct EdgeIdx { int node0, node, k, nbn, Mt; };

static __device__ __forceinline__ EdgeIdx edge_idx(int wave, int it, int lcol) {
    EdgeIdx e;
    int p = (it >= 3) ? 1 : 0;
    e.Mt = it - 3 * p;
    e.node0 = wave * 4 + p * 2;
    int ke = e.Mt * 16 + lcol;
    int nsel = (ke >= 24) ? 1 : 0;
    e.node = e.node0 + nsel;
    e.k = ke - 24 * nsel;
    int bb = e.node >> 14;
    int nl = e.node & (NNODES - 1);
    int yy = nl >> 7, xx = nl & 127;
    int kk = e.k + (e.k >= 12 ? 1 : 0);
    int q5 = (kk * 52) >> 8;
    int dy = q5 - 2, dx = kk - 5 * q5 - 2;
    int ny = min(max(yy + dy, 0), 127);
    int nx = min(max(xx + dx, 0), 127);
    e.nbn = (bb << 14) + (ny << 7) + nx;
    return e;
}

__global__ __launch_bounds__(256, 4) void score_k(
    const float* __restrict__ zsrc, const float* __restrict__ ztgt,
    const float* __restrict__ zpos, const float* __restrict__ W2,
    const float* __restrict__ b2, const float* __restrict__ W3,
    const float* __restrict__ b3, float* __restrict__ scores)
{
    __shared__ fragcast fraglds[64 * 13];   // lane-major, pad 13 -> conflict-free

    const int t = threadIdx.x;
    const int l = t & 63;
    const int lcol = l & 15;
    const int lgrp = l >> 4;
    const int wave = blockIdx.x * 4 + (t >> 6);   // 8192 waves x 4 nodes

    // ---- W2 fragment init (wave 0), exact 3-way split ----
    if (t < 64) {
        #pragma unroll
        for (int jt = 0; jt < 2; ++jt)
            #pragma unroll
            for (int kt = 0; kt < 2; ++kt) {
                fragcast fh, fl, fl2;
                const float* wr = W2 + (size_t)(jt * 16 + lcol) * 64 + kt * 32 + lgrp * 8;
                #pragma unroll
                for (int d = 0; d < 4; ++d) {
                    unsigned h0, l0, m0, h1, l1, m1;
                    split3(wr[2 * d],     h0, l0, m0);
                    split3(wr[2 * d + 1], h1, l1, m1);
                    fh.u[d]  = pack_hi16(h0, h1);
                    fl.u[d]  = pack_hi16(l0, l1);
                    fl2.u[d] = pack_hi16(m0, m1);
                }
                fraglds[l * 13 + (0 + jt * 2 + kt)] = fh;
                fraglds[l * 13 + (4 + jt * 2 + kt)] = fl;
                fraglds[l * 13 + (8 + jt * 2 + kt)] = fl2;
            }
    }
    __syncthreads();

    const fragcast* fb = &fraglds[l * 13];
    const f32x4 b2l0 = *(const f32x4*)(b2 + lgrp * 4);
    const f32x4 b2l1 = *(const f32x4*)(b2 + 16 + lgrp * 4);
    const f32x4 w3l0 = *(const f32x4*)(W3 + lgrp * 4);
    const f32x4 w3l1 = *(const f32x4*)(W3 + 16 + lgrp * 4);
    const float b3s = b3[0];

#define ISSUE(E, T0A, T1A, T0B, T1B) { \
        const float* zt_ = ztgt + (size_t)(E).nbn * 64 + lgrp * 8; \
        T0A = *(const float4*)(zt_);      T1A = *(const float4*)(zt_ + 4); \
        T0B = *(const float4*)(zt_ + 32); T1B = *(const float4*)(zt_ + 36); }

#define BODY(E, T0A, T1A, T0B, T1B) { \
        f32x4 ac0A = {0.f,0.f,0.f,0.f}, ac0B = {0.f,0.f,0.f,0.f}; \
        f32x4 ac1A = {0.f,0.f,0.f,0.f}, ac1B = {0.f,0.f,0.f,0.f}; \
        _Pragma("unroll") \
        for (int kt = 0; kt < 2; ++kt) { \
            const int c0 = kt * 32 + lgrp * 8; \
            float4 a0 = *(const float4*)(zsrc + (size_t)(E).node * 64 + c0); \
            float4 a1 = *(const float4*)(zsrc + (size_t)(E).node * 64 + c0 + 4); \
            float4 p0 = *(const float4*)(zpos + (E).k * 64 + c0); \
            float4 p1 = *(const float4*)(zpos + (E).k * 64 + c0 + 4); \
            float4 t0 = kt ? T0B : T0A; \
            float4 t1 = kt ? T1B : T1A; \
            float v[8]; \
            v[0] = fmaxf(a0.x + t0.x + p0.x, 0.f); \
            v[1] = fmaxf(a0.y + t0.y + p0.y, 0.f); \
            v[2] = fmaxf(a0.z + t0.z + p0.z, 0.f); \
            v[3] = fmaxf(a0.w + t0.w + p0.w, 0.f); \
            v[4] = fmaxf(a1.x + t1.x + p1.x, 0.f); \
            v[5] = fmaxf(a1.y + t1.y + p1.y, 0.f); \
            v[6] = fmaxf(a1.z + t1.z + p1.z, 0.f); \
            v[7] = fmaxf(a1.w + t1.w + p1.w, 0.f); \
            fragcast Bh, Bl, Bl2; \
            _Pragma("unroll") \
            for (int d = 0; d < 4; ++d) { \
                unsigned h0, l0, m0, h1, l1, m1; \
                split3(v[2 * d],     h0, l0, m0); \
                split3(v[2 * d + 1], h1, l1, m1); \
                Bh.u[d]  = pack_hi16(h0, h1); \
                Bl.u[d]  = pack_hi16(l0, l1); \
                Bl2.u[d] = pack_hi16(m0, m1); \
            } \
            bf16x8 Ah0  = fb[0 + 0 + kt].b; \
            bf16x8 Ah1  = fb[0 + 2 + kt].b; \
            bf16x8 Al0  = fb[4 + 0 + kt].b; \
            bf16x8 Al1  = fb[4 + 2 + kt].b; \
            bf16x8 Al20 = fb[8 + 0 + kt].b; \
            bf16x8 Al21 = fb[8 + 2 + kt].b; \
            ac0A = __builtin_amdgcn_mfma_f32_16x16x32_bf16(Ah0,  Bh.b,  ac0A, 0, 0, 0); \
            ac1A = __builtin_amdgcn_mfma_f32_16x16x32_bf16(Ah1,  Bh.b,  ac1A, 0, 0, 0); \
            ac0B = __builtin_amdgcn_mfma_f32_16x16x32_bf16(Al0,  Bh.b,  ac0B, 0, 0, 0); \
            ac1B = __builtin_amdgcn_mfma_f32_16x16x32_bf16(Al1,  Bh.b,  ac1B, 0, 0, 0); \
            ac0A = __builtin_amdgcn_mfma_f32_16x16x32_bf16(Al20, Bh.b,  ac0A, 0, 0, 0); \
            ac1A = __builtin_amdgcn_mfma_f32_16x16x32_bf16(Al21, Bh.b,  ac1A, 0, 0, 0); \
            ac0B = __builtin_amdgcn_mfma_f32_16x16x32_bf16(Ah0,  Bl.b,  ac0B, 0, 0, 0); \
            ac1B = __builtin_amdgcn_mfma_f32_16x16x32_bf16(Ah1,  Bl.b,  ac1B, 0, 0, 0); \
            ac0A = __builtin_amdgcn_mfma_f32_16x16x32_bf16(Al0,  Bl.b,  ac0A, 0, 0, 0); \
            ac1A = __builtin_amdgcn_mfma_f32_16x16x32_bf16(Al1,  Bl.b,  ac1A, 0, 0, 0); \
            ac0B = __builtin_amdgcn_mfma_f32_16x16x32_bf16(Ah0,  Bl2.b, ac0B, 0, 0, 0); \
            ac1B = __builtin_amdgcn_mfma_f32_16x16x32_bf16(Ah1,  Bl2.b, ac1B, 0, 0, 0); \
        } \
        const f32x4 s0 = ac0A + ac0B; \
        const f32x4 s1 = ac1A + ac1B; \
        float sacc = 0.f; \
        _Pragma("unroll") \
        for (int q = 0; q < 4; ++q) { \
            sacc = fmaf(fmaxf(s0[q] + b2l0[q], 0.f), w3l0[q], sacc); \
            sacc = fmaf(fmaxf(s1[q] + b2l1[q], 0.f), w3l1[q], sacc); \
        } \
        sacc += __shfl_xor(sacc, 16); \
        sacc += __shfl_xor(sacc, 32); \
        float sig = 1.f / (1.f + expf(-(sacc + b3s))); \
        if (l < 16) \
            scores[(size_t)(E).node0 * 24 + (E).Mt * 16 + l] = sig; }

    EdgeIdx eE = edge_idx(wave, 0, lcol);
    float4 a0A, a1A, a2A, a3A;   // buffer A (even iterations)
    float4 a0B, a1B, a2B, a3B;   // buffer B (odd iterations)
    ISSUE(eE, a0A, a1A, a2A, a3A);

    #pragma unroll 1
    for (int it2 = 0; it2 < 3; ++it2) {
        const int itE = 2 * it2;
        EdgeIdx eO = edge_idx(wave, itE + 1, lcol);
        ISSUE(eO, a0B, a1B, a2B, a3B);          // hides under even body
        BODY(eE, a0A, a1A, a2A, a3A);
        EdgeIdx eN = eE;
        if (it2 < 2) {
            eN = edge_idx(wave, itE + 2, lcol);
            ISSUE(eN, a0A, a1A, a2A, a3A);      // hides under odd body
        }
        BODY(eO, a0B, a1B, a2B, a3B);
        eE = eN;
    }
#undef ISSUE
#undef BODY
}

// ---------------------------------------------------------------------------
// C: per-node rank/mask/weights + weighted msg aggregation + Wo + residual.
// ---------------------------------------------------------------------------
__global__ __launch_bounds__(256) void agg_k(
    const float* __restrict__ x, const float* __restrict__ scores,
    const float* __restrict__ msg, const float* __restrict__ Wo,
    const float* __restrict__ bo, const float* __restrict__ thrp,
    float* __restrict__ out)
{
    __shared__ float sc[768];
    __shared__ float wl[768];
    __shared__ float sumw[32];
    __shared__ float aggL[32][64];
    __shared__ float ot[64][33];

    const int t = threadIdx.x;
    const int n0 = blockIdx.x * 32;
    const int b = n0 >> 14;
    const int nl0 = n0 & (NNODES - 1);
    const float thr_v = 1.f / (1.f + expf(-thrp[0]));

    #pragma unroll
    for (int rep = 0; rep < 3; ++rep)
        sc[rep * 256 + t] = scores[(size_t)n0 * 24 + rep * 256 + t];
    __syncthreads();

    #pragma unroll
    for (int rep = 0; rep < 3; ++rep) {
        int e = rep * 256 + t;
        int nl = (int)(((unsigned)(e >> 3) * 171u) >> 9);   // e/24 for e<768
        int k = e - nl * 24;
        float s_e = sc[e];
        int rank = 0, cnt = 0;
        #pragma unroll
        for (int j = 0; j < 24; ++j) {
            float sj = sc[nl * 24 + j];
            rank += (sj > s_e || (sj == s_e && j < k)) ? 1 : 0;
            cnt  += (sj >= thr_v) ? 1 : 0;
        }
        bool mask = (cnt > 8) ? (rank < 8)
                  : ((cnt < 3) ? (rank < 3) : (s_e >= thr_v));
        float keep = 1.f / (1.f + expf(-(s_e - thr_v) * 10.f));
        wl[e] = mask ? s_e * keep : 0.f;
    }
    __syncthreads();

    if (t < 32) {
        float s = 0.f;
        #pragma unroll
        for (int k = 0; k < 24; ++k) s += wl[t * 24 + k];
        sumw[t] = s + 1e-6f;
    }
    __syncthreads();

    const int lane = t & 63;
    const int g4 = t >> 6;

    #pragma unroll
    for (int it = 0; it < 8; ++it) {
        int nl = g4 + it * 4;
        int nn = nl0 + nl;
        int yy = nn >> 7, xx = nn & 127;
        float acc = 0.f;
        #pragma unroll
        for (int k = 0; k < 24; ++k) {
            int kk = k + (k >= 12 ? 1 : 0);
            int q5 = (kk * 52) >> 8;
            int dy = q5 - 2, dx = kk - 5 * q5 - 2;
            int ny = min(max(yy + dy, 0), 127);
            int nx = min(max(xx + dx, 0), 127);
            int nb = (b << 14) + (ny << 7) + nx;
            acc = fmaf(wl[nl * 24 + k], msg[(size_t)nb * 64 + lane], acc);
        }
        aggL[nl][lane] = acc / sumw[nl];
    }

    float4 wo[16];
    #pragma unroll
    for (int c4 = 0; c4 < 16; ++c4) wo[c4] = ((const float4*)Wo)[lane * 16 + c4];
    __syncthreads();

    #pragma unroll
    for (int it = 0; it < 8; ++it) {
        int nl = g4 + it * 4;
        const float4* ar = (const float4*)aggL[nl];
        float a0 = 0.f, a1 = 0.f, a2 = 0.f, a3 = 0.f;
        #pragma unroll
        for (int c4 = 0; c4 < 16; ++c4) {
            float4 wv = wo[c4];
            float4 av = ar[c4];
            a0 = fmaf(av.x, wv.x, a0);
            a1 = fmaf(av.y, wv.y, a1);
            a2 = fmaf(av.z, wv.z, a2);
            a3 = fmaf(av.w, wv.w, a3);
        }
        float v = (a0 + a1) + (a2 + a3) + bo[lane]
                + x[(size_t)b * 64 * NNODES + (size_t)lane * NNODES + nl0 + nl];
        ot[lane][nl] = v;
    }
    __syncthreads();

    #pragma unroll
    for (int rep = 0; rep < 2; ++rep) {
        int idx = rep * 256 + t;
        int o = idx >> 3, p = idx & 7;
        float4 v = make_float4(ot[o][4 * p + 0], ot[o][4 * p + 1],
                               ot[o][4 * p + 2], ot[o][4 * p + 3]);
        *(float4*)(out + (size_t)b * 64 * NNODES + (size_t)o * NNODES + nl0 + 4 * p) = v;
    }
}

// ---------------------------------------------------------------------------
extern "C" void kernel_launch(void* const* d_in, const int* in_sizes, int n_in,
                              void* d_out, int out_size, void* d_ws, size_t ws_size,
                              hipStream_t stream)
{
    const float* x   = (const float*)d_in[0];
    const float* W1  = (const float*)d_in[1];
    const float* b1  = (const float*)d_in[2];
    const float* W2  = (const float*)d_in[3];
    const float* b2  = (const float*)d_in[4];
    const float* W3  = (const float*)d_in[5];
    const float* b3  = (const float*)d_in[6];
    const float* thr = (const float*)d_in[7];
    const float* Wm  = (const float*)d_in[8];
    const float* bm  = (const float*)d_in[9];
    const float* Wo  = (const float*)d_in[10];
    const float* bo  = (const float*)d_in[11];
    float* out = (float*)d_out;
    float* ws  = (float*)d_ws;

    // ws layout (floats): zsrc[2M] ztgt[2M] msg[2M] scores[768K] zpos[1536]
    float* zsrc   = ws;
    float* ztgt   = ws + 2097152;
    float* msg    = ws + 4194304;
    float* scores = ws + 6291456;
    float* zpos   = ws + 7077888;

    hipLaunchKernelGGL(aux_k, dim3(1), dim3(256), 0, stream, W1, zpos);
    hipLaunchKernelGGL(precompute_k, dim3(768), dim3(128), 0, stream,
                       x, W1, Wm, b1, bm, zsrc, ztgt, msg);
    hipLaunchKernelGGL(score_k, dim3(2048), dim3(256), 0, stream,
                       zsrc, ztgt, zpos, W2, b2, W3, b3, scores);
    hipLaunchKernelGGL(agg_k, dim3(1024), dim3(256), 0, stream,
                       x, scores, msg, Wo, bo, thr, out);
}

// Round 10
// 98.904 us; speedup vs baseline: 1.9037x; 1.3471x over previous
//
#include <hip/hip_runtime.h>
#include <hip/hip_bf16.h>
#include <math.h>

// Problem constants (B,C,H,W) = (2,64,128,128), R=2 -> K=24 neighbors.
#define NNODES 16384            // H*W
#define KE 24

typedef float f32x4 __attribute__((ext_vector_type(4)));
typedef short bf16x8 __attribute__((ext_vector_type(8)));
typedef unsigned u32x4 __attribute__((ext_vector_type(4)));

union fragcast { u32x4 u; bf16x8 b; };

// Exact 3-way truncation split: v == hi + lo + lo2 (all bf16-representable).
static __device__ __forceinline__ void split3(float v, unsigned& uh,
                                              unsigned& ul, unsigned& um) {
    union { float f; unsigned u; } a; a.f = v;
    uh = a.u & 0xFFFF0000u;
    union { unsigned u; float f; } h; h.u = uh;
    float r1 = v - h.f;                      // exact
    union { float f; unsigned u; } b; b.f = r1;
    ul = b.u & 0xFFFF0000u;
    union { unsigned u; float f; } l; l.u = ul;
    float r2 = r1 - l.f;                     // exact, <= 8 sig bits
    union { float f; unsigned u; } c; c.f = r2;
    um = c.u;                                // top 16 bits == exact bf16
}

static __device__ __forceinline__ unsigned pack_hi16(unsigned even, unsigned odd) {
    return __builtin_amdgcn_perm(odd, even, 0x07060302u);   // v_perm_b32
}

// ---------------------------------------------------------------------------
// aux: zpos[k][h] table only
// ---------------------------------------------------------------------------
__global__ void aux_k(const float* __restrict__ W1, float* __restrict__ zpos)
{
    int t = threadIdx.x;
    for (int idx = t; idx < KE * 64; idx += 256) {
        int k = idx >> 6, h = idx & 63;
        int kk = k + (k >= 12 ? 1 : 0);       // skip center of 5x5
        int q5 = (kk * 52) >> 8;              // kk/5 for kk<25
        int dy = q5 - 2;
        int dx = kk - 5 * q5 - 2;
        zpos[idx] = W1[h * 130 + 128] * (dx * 0.5f)
                  + W1[h * 130 + 129] * (dy * 0.5f);
    }
}

// ---------------------------------------------------------------------------
// A: per-node precompute (absorbs weight transpose). 128 thr, 8h x 8n tiles.
// ---------------------------------------------------------------------------
__global__ __launch_bounds__(128) void precompute_k(
    const float* __restrict__ x, const float* __restrict__ W1,
    const float* __restrict__ Wm, const float* __restrict__ b1,
    const float* __restrict__ bm,
    float* __restrict__ zsrc, float* __restrict__ ztgt, float* __restrict__ msg)
{
    __shared__ float xt[64][128];   // [c][node]  32 KB
    __shared__ float wl[64][64];    // [c][h]     16 KB
    const int t = threadIdx.x;
    const int mat = blockIdx.x >> 8;        // grid = 3*256
    const int tile = blockIdx.x & 255;
    const int n0 = tile * 128;
    const int b = n0 >> 14;
    const int nl0 = n0 & (NNODES - 1);
    const float* xb = x + (size_t)b * 64 * NNODES + nl0;

    #pragma unroll
    for (int r = 0; r < 16; ++r) {
        int idx = r * 128 + t;
        int c = idx >> 5, j4 = idx & 31;
        float4 v = *(const float4*)(xb + (size_t)c * NNODES + j4 * 4);
        *(float4*)&xt[c][j4 * 4] = v;
    }
    #pragma unroll
    for (int r = 0; r < 32; ++r) {
        int idx = r * 128 + t;
        int c = idx >> 6, h = idx & 63;
        float v = (mat == 0) ? W1[h * 130 + c]
                : (mat == 1) ? W1[h * 130 + 64 + c]
                             : Wm[h * 64 + c];
        (&wl[0][0])[idx] = v;
    }
    __syncthreads();

    const int i = t >> 4;   // h-octet
    const int j = t & 15;   // node-group

    float acc[8][8];
    #pragma unroll
    for (int a = 0; a < 8; ++a)
        #pragma unroll
        for (int bb = 0; bb < 8; ++bb) acc[a][bb] = 0.f;

    #pragma unroll 4
    for (int c = 0; c < 64; ++c) {
        float4 w0 = *(const float4*)&wl[c][i * 8];
        float4 w1 = *(const float4*)&wl[c][i * 8 + 4];
        float4 x0 = *(const float4*)&xt[c][j * 8];
        float4 x1 = *(const float4*)&xt[c][j * 8 + 4];
        float wv[8] = {w0.x, w0.y, w0.z, w0.w, w1.x, w1.y, w1.z, w1.w};
        float xv[8] = {x0.x, x0.y, x0.z, x0.w, x1.x, x1.y, x1.z, x1.w};
        #pragma unroll
        for (int a = 0; a < 8; ++a)
            #pragma unroll
            for (int bb = 0; bb < 8; ++bb)
                acc[a][bb] = fmaf(wv[a], xv[bb], acc[a][bb]);
    }

    #pragma unroll
    for (int a = 0; a < 8; ++a) {
        float bv = (mat == 0) ? b1[i * 8 + a] : (mat == 2) ? bm[i * 8 + a] : 0.f;
        #pragma unroll
        for (int bb = 0; bb < 8; ++bb) {
            float v = acc[a][bb] + bv;
            acc[a][bb] = (mat == 2) ? fmaxf(v, 0.f) : v;
        }
    }

    float* dst = (mat == 0) ? zsrc : (mat == 1) ? ztgt : msg;
    #pragma unroll
    for (int nn = 0; nn < 8; ++nn) {
        float* o = dst + (size_t)(n0 + j * 8 + nn) * 64 + i * 8;
        *(float4*)o       = make_float4(acc[0][nn], acc[1][nn], acc[2][nn], acc[3][nn]);
        *(float4*)(o + 4) = make_float4(acc[4][nn], acc[5][nn], acc[6][nn], acc[7][nn]);
    }
}

// ---------------------------------------------------------------------------
// B: scorer. Exact 3-way-split bf16 MFMA. Minimal spill-free body:
//    no pipelining; W2 frags in conflict-free LDS (l*13 stride, measured 0
//    conflicts); zpos in LDS (pad 68); plain loops, unroll 1 on pair loop.
// ---------------------------------------------------------------------------
__global__ __launch_bounds__(256, 3) void score_k(
    const float* __restrict__ zsrc, const float* __restrict__ ztgt,
    const float* __restrict__ zpos, const float* __restrict__ W2,
    const float* __restrict__ b2, const float* __restrict__ W3,
    const float* __restrict__ b3, float* __restrict__ scores)
{
    __shared__ fragcast fraglds[64 * 13];   // 13 KB, lane-major stride 13
    __shared__ float zpl[24 * 68];          // 6.5 KB, padded rows

    const int t = threadIdx.x;
    const int l = t & 63;
    const int lcol = l & 15;
    const int lgrp = l >> 4;
    const int w = t >> 6;
    const int wave = blockIdx.x * 4 + w;    // 8192 waves x 4 nodes

    // stage zpos (coalesced)
    #pragma unroll
    for (int r = 0; r < 6; ++r) {
        int idx = r * 256 + t;
        zpl[(idx >> 6) * 68 + (idx & 63)] = zpos[idx];
    }
    // W2 fragments: wave w builds quadrant (jt = w>>1, kt = w&1)
    {
        const int jt = w >> 1, kt = w & 1;
        fragcast fh, fl, fl2;
        const float* wr = W2 + (size_t)(jt * 16 + lcol) * 64 + kt * 32 + lgrp * 8;
        #pragma unroll
        for (int d = 0; d < 4; ++d) {
            unsigned h0, l0, m0, h1, l1, m1;
            split3(wr[2 * d],     h0, l0, m0);
            split3(wr[2 * d + 1], h1, l1, m1);
            fh.u[d]  = pack_hi16(h0, h1);
            fl.u[d]  = pack_hi16(l0, l1);
            fl2.u[d] = pack_hi16(m0, m1);
        }
        fraglds[l * 13 + 0 + jt * 2 + kt] = fh;
        fraglds[l * 13 + 4 + jt * 2 + kt] = fl;
        fraglds[l * 13 + 8 + jt * 2 + kt] = fl2;
    }
    __syncthreads();

    const fragcast* fb = &fraglds[l * 13];
    const f32x4 b2l0 = *(const f32x4*)(b2 + lgrp * 4);
    const f32x4 b2l1 = *(const f32x4*)(b2 + 16 + lgrp * 4);
    const f32x4 w3l0 = *(const f32x4*)(W3 + lgrp * 4);
    const f32x4 w3l1 = *(const f32x4*)(W3 + 16 + lgrp * 4);
    const float b3s = b3[0];

    #pragma unroll 1
    for (int p = 0; p < 2; ++p) {
        const int node0 = wave * 4 + p * 2;

        #pragma unroll
        for (int Mt = 0; Mt < 3; ++Mt) {
            const int ke = Mt * 16 + lcol;
            const int nsel = (ke >= 24) ? 1 : 0;
            const int node = node0 + nsel;
            const int k = ke - 24 * nsel;
            const int bb = node >> 14;
            const int nl = node & (NNODES - 1);
            const int yy = nl >> 7, xx = nl & 127;
            const int kk = k + (k >= 12 ? 1 : 0);
            const int q5 = (kk * 52) >> 8;
            const int dy = q5 - 2, dx = kk - 5 * q5 - 2;
            const int ny = min(max(yy + dy, 0), 127);
            const int nx = min(max(xx + dx, 0), 127);
            const int nbn = (bb << 14) + (ny << 7) + nx;

            const float* zs = zsrc + (size_t)node * 64 + lgrp * 8;
            const float* zt = ztgt + (size_t)nbn * 64 + lgrp * 8;
            const float* zp = &zpl[k * 68 + lgrp * 8];

            f32x4 ac0A = {0.f,0.f,0.f,0.f}, ac0B = {0.f,0.f,0.f,0.f};
            f32x4 ac1A = {0.f,0.f,0.f,0.f}, ac1B = {0.f,0.f,0.f,0.f};

            #pragma unroll
            for (int kt = 0; kt < 2; ++kt) {
                const int o = kt * 32;
                float4 a0 = *(const float4*)(zs + o);
                float4 a1 = *(const float4*)(zs + o + 4);
                float4 t0 = *(const float4*)(zt + o);
                float4 t1 = *(const float4*)(zt + o + 4);
                float4 p0 = *(const float4*)(zp + o);
                float4 p1 = *(const float4*)(zp + o + 4);
                float v[8];
                v[0] = fmaxf(a0.x + t0.x + p0.x, 0.f);
                v[1] = fmaxf(a0.y + t0.y + p0.y, 0.f);
                v[2] = fmaxf(a0.z + t0.z + p0.z, 0.f);
                v[3] = fmaxf(a0.w + t0.w + p0.w, 0.f);
                v[4] = fmaxf(a1.x + t1.x + p1.x, 0.f);
                v[5] = fmaxf(a1.y + t1.y + p1.y, 0.f);
                v[6] = fmaxf(a1.z + t1.z + p1.z, 0.f);
                v[7] = fmaxf(a1.w + t1.w + p1.w, 0.f);

                fragcast Bh, Bl, Bl2;
                #pragma unroll
                for (int d = 0; d < 4; ++d) {
                    unsigned h0, l0, m0, h1, l1, m1;
                    split3(v[2 * d],     h0, l0, m0);
                    split3(v[2 * d + 1], h1, l1, m1);
                    Bh.u[d]  = pack_hi16(h0, h1);
                    Bl.u[d]  = pack_hi16(l0, l1);
                    Bl2.u[d] = pack_hi16(m0, m1);
                }

                bf16x8 Ah0  = fb[0 + kt].b;      // jt=0 hi
                bf16x8 Ah1  = fb[2 + kt].b;      // jt=1 hi
                bf16x8 Al0  = fb[4 + kt].b;      // jt=0 lo
                bf16x8 Al1  = fb[6 + kt].b;      // jt=1 lo
                bf16x8 Al20 = fb[8 + kt].b;      // jt=0 lo2
                bf16x8 Al21 = fb[10 + kt].b;     // jt=1 lo2

                ac0A = __builtin_amdgcn_mfma_f32_16x16x32_bf16(Ah0,  Bh.b,  ac0A, 0, 0, 0);
                ac1A = __builtin_amdgcn_mfma_f32_16x16x32_bf16(Ah1,  Bh.b,  ac1A, 0, 0, 0);
                ac0B = __builtin_amdgcn_mfma_f32_16x16x32_bf16(Al0,  Bh.b,  ac0B, 0, 0, 0);
                ac1B = __builtin_amdgcn_mfma_f32_16x16x32_bf16(Al1,  Bh.b,  ac1B, 0, 0, 0);
                ac0A = __builtin_amdgcn_mfma_f32_16x16x32_bf16(Al20, Bh.b,  ac0A, 0, 0, 0);
                ac1A = __builtin_amdgcn_mfma_f32_16x16x32_bf16(Al21, Bh.b,  ac1A, 0, 0, 0);
                ac0B = __builtin_amdgcn_mfma_f32_16x16x32_bf16(Ah0,  Bl.b,  ac0B, 0, 0, 0);
                ac1B = __builtin_amdgcn_mfma_f32_16x16x32_bf16(Ah1,  Bl.b,  ac1B, 0, 0, 0);
                ac0A = __builtin_amdgcn_mfma_f32_16x16x32_bf16(Al0,  Bl.b,  ac0A, 0, 0, 0);
                ac1A = __builtin_amdgcn_mfma_f32_16x16x32_bf16(Al1,  Bl.b,  ac1A, 0, 0, 0);
                ac0B = __builtin_amdgcn_mfma_f32_16x16x32_bf16(Ah0,  Bl2.b, ac0B, 0, 0, 0);
                ac1B = __builtin_amdgcn_mfma_f32_16x16x32_bf16(Ah1,  Bl2.b, ac1B, 0, 0, 0);
            }

            const f32x4 s0 = ac0A + ac0B;
            const f32x4 s1 = ac1A + ac1B;
            float sacc = 0.f;
            #pragma unroll
            for (int q = 0; q < 4; ++q) {
                sacc = fmaf(fmaxf(s0[q] + b2l0[q], 0.f), w3l0[q], sacc);
                sacc = fmaf(fmaxf(s1[q] + b2l1[q], 0.f), w3l1[q], sacc);
            }
            sacc += __shfl_xor(sacc, 16);
            sacc += __shfl_xor(sacc, 32);
            float sig = 1.f / (1.f + expf(-(sacc + b3s)));
            if (l < 16)
                scores[(size_t)node0 * 24 + Mt * 16 + l] = sig;
        }
    }
}

// ---------------------------------------------------------------------------
// C: per-node rank/mask/weights + weighted msg aggregation + Wo + residual.
// ---------------------------------------------------------------------------
__global__ __launch_bounds__(256) void agg_k(
    const float* __restrict__ x, const float* __restrict__ scores,
    const float* __restrict__ msg, const float* __restrict__ Wo,
    const float* __restrict__ bo, const float* __restrict__ thrp,
    float* __restrict__ out)
{
    __shared__ float sc[768];
    __shared__ float wl[768];
    __shared__ float sumw[32];
    __shared__ float aggL[32][64];
    __shared__ float ot[64][33];

    const int t = threadIdx.x;
    const int n0 = blockIdx.x * 32;
    const int b = n0 >> 14;
    const int nl0 = n0 & (NNODES - 1);
    const float thr_v = 1.f / (1.f + expf(-thrp[0]));

    #pragma unroll
    for (int rep = 0; rep < 3; ++rep)
        sc[rep * 256 + t] = scores[(size_t)n0 * 24 + rep * 256 + t];
    __syncthreads();

    #pragma unroll
    for (int rep = 0; rep < 3; ++rep) {
        int e = rep * 256 + t;
        int nl = (int)(((unsigned)(e >> 3) * 171u) >> 9);   // e/24 for e<768
        int k = e - nl * 24;
        float s_e = sc[e];
        int rank = 0, cnt = 0;
        #pragma unroll
        for (int j = 0; j < 24; ++j) {
            float sj = sc[nl * 24 + j];
            rank += (sj > s_e || (sj == s_e && j < k)) ? 1 : 0;
            cnt  += (sj >= thr_v) ? 1 : 0;
        }
        bool mask = (cnt > 8) ? (rank < 8)
                  : ((cnt < 3) ? (rank < 3) : (s_e >= thr_v));
        float keep = 1.f / (1.f + expf(-(s_e - thr_v) * 10.f));
        wl[e] = mask ? s_e * keep : 0.f;
    }
    __syncthreads();

    if (t < 32) {
        float s = 0.f;
        #pragma unroll
        for (int k = 0; k < 24; ++k) s += wl[t * 24 + k];
        sumw[t] = s + 1e-6f;
    }
    __syncthreads();

    const int lane = t & 63;
    const int g4 = t >> 6;

    #pragma unroll
    for (int it = 0; it < 8; ++it) {
        int nl = g4 + it * 4;
        int nn = nl0 + nl;
        int yy = nn >> 7, xx = nn & 127;
        float acc = 0.f;
        #pragma unroll
        for (int k = 0; k < 24; ++k) {
            int kk = k + (k >= 12 ? 1 : 0);
            int q5 = (kk * 52) >> 8;
            int dy = q5 - 2, dx = kk - 5 * q5 - 2;
            int ny = min(max(yy + dy, 0), 127);
            int nx = min(max(xx + dx, 0), 127);
            int nb = (b << 14) + (ny << 7) + nx;
            acc = fmaf(wl[nl * 24 + k], msg[(size_t)nb * 64 + lane], acc);
        }
        aggL[nl][lane] = acc / sumw[nl];
    }

    float4 wo[16];
    #pragma unroll
    for (int c4 = 0; c4 < 16; ++c4) wo[c4] = ((const float4*)Wo)[lane * 16 + c4];
    __syncthreads();

    #pragma unroll
    for (int it = 0; it < 8; ++it) {
        int nl = g4 + it * 4;
        const float4* ar = (const float4*)aggL[nl];
        float a0 = 0.f, a1 = 0.f, a2 = 0.f, a3 = 0.f;
        #pragma unroll
        for (int c4 = 0; c4 < 16; ++c4) {
            float4 wv = wo[c4];
            float4 av = ar[c4];
            a0 = fmaf(av.x, wv.x, a0);
            a1 = fmaf(av.y, wv.y, a1);
            a2 = fmaf(av.z, wv.z, a2);
            a3 = fmaf(av.w, wv.w, a3);
        }
        float v = (a0 + a1) + (a2 + a3) + bo[lane]
                + x[(size_t)b * 64 * NNODES + (size_t)lane * NNODES + nl0 + nl];
        ot[lane][nl] = v;
    }
    __syncthreads();

    #pragma unroll
    for (int rep = 0; rep < 2; ++rep) {
        int idx = rep * 256 + t;
        int o = idx >> 3, p = idx & 7;
        float4 v = make_float4(ot[o][4 * p + 0], ot[o][4 * p + 1],
                               ot[o][4 * p + 2], ot[o][4 * p + 3]);
        *(float4*)(out + (size_t)b * 64 * NNODES + (size_t)o * NNODES + nl0 + 4 * p) = v;
    }
}

// ---------------------------------------------------------------------------
extern "C" void kernel_launch(void* const* d_in, const int* in_sizes, int n_in,
                              void* d_out, int out_size, void* d_ws, size_t ws_size,
                              hipStream_t stream)
{
    const float* x   = (const float*)d_in[0];
    const float* W1  = (const float*)d_in[1];
    const float* b1  = (const float*)d_in[2];
    const float* W2  = (const float*)d_in[3];
    const float* b2  = (const float*)d_in[4];
    const float* W3  = (const float*)d_in[5];
    const float* b3  = (const float*)d_in[6];
    const float* thr = (const float*)d_in[7];
    const float* Wm  = (const float*)d_in[8];
    const float* bm  = (const float*)d_in[9];
    const float* Wo  = (const float*)d_in[10];
    const float* bo  = (const float*)d_in[11];
    float* out = (float*)d_out;
    float* ws  = (float*)d_ws;

    // ws layout (floats): zsrc[2M] ztgt[2M] msg[2M] scores[768K] zpos[1536]
    float* zsrc   = ws;
    float* ztgt   = ws + 2097152;
    float* msg    = ws + 4194304;
    float* scores = ws + 6291456;
    float* zpos   = ws + 7077888;

    hipLaunchKernelGGL(aux_k, dim3(1), dim3(256), 0, stream, W1, zpos);
    hipLaunchKernelGGL(precompute_k, dim3(768), dim3(128), 0, stream,
                       x, W1, Wm, b1, bm, zsrc, ztgt, msg);
    hipLaunchKernelGGL(score_k, dim3(2048), dim3(256), 0, stream,
                       zsrc, ztgt, zpos, W2, b2, W3, b3, scores);
    hipLaunchKernelGGL(agg_k, dim3(1024), dim3(256), 0, stream,
                       x, scores, msg, Wo, bo, thr, out);
}

// Round 11
// 94.168 us; speedup vs baseline: 1.9995x; 1.0503x over previous
//
#include <hip/hip_runtime.h>
#include <hip/hip_bf16.h>
#include <math.h>

// Problem constants (B,C,H,W) = (2,64,128,128), R=2 -> K=24 neighbors.
#define NNODES 16384            // H*W
#define KE 24

typedef float f32x4 __attribute__((ext_vector_type(4)));
typedef short bf16x8 __attribute__((ext_vector_type(8)));
typedef unsigned u32x4 __attribute__((ext_vector_type(4)));

union fragcast { u32x4 u; bf16x8 b; };

// Exact 3-way truncation split: v == hi + lo + lo2 (all bf16-representable).
static __device__ __forceinline__ void split3(float v, unsigned& uh,
                                              unsigned& ul, unsigned& um) {
    union { float f; unsigned u; } a; a.f = v;
    uh = a.u & 0xFFFF0000u;
    union { unsigned u; float f; } h; h.u = uh;
    float r1 = v - h.f;                      // exact
    union { float f; unsigned u; } b; b.f = r1;
    ul = b.u & 0xFFFF0000u;
    union { unsigned u; float f; } l; l.u = ul;
    float r2 = r1 - l.f;                     // exact, <= 8 sig bits
    union { float f; unsigned u; } c; c.f = r2;
    um = c.u;                                // top 16 bits == exact bf16
}

static __device__ __forceinline__ unsigned pack_hi16(unsigned even, unsigned odd) {
    return __builtin_amdgcn_perm(odd, even, 0x07060302u);   // v_perm_b32
}

// ---------------------------------------------------------------------------
// A: per-node precompute (absorbs weight transpose AND the zpos table).
//    128 thr, 8h x 8n tiles. Block 0 additionally writes zpos.
// ---------------------------------------------------------------------------
__global__ __launch_bounds__(128) void precompute_k(
    const float* __restrict__ x, const float* __restrict__ W1,
    const float* __restrict__ Wm, const float* __restrict__ b1,
    const float* __restrict__ bm,
    float* __restrict__ zsrc, float* __restrict__ ztgt, float* __restrict__ msg,
    float* __restrict__ zpos)
{
    __shared__ float xt[64][128];   // [c][node]  32 KB
    __shared__ float wl[64][64];    // [c][h]     16 KB
    const int t = threadIdx.x;
    const int mat = blockIdx.x >> 8;        // grid = 3*256
    const int tile = blockIdx.x & 255;
    const int n0 = tile * 128;
    const int b = n0 >> 14;
    const int nl0 = n0 & (NNODES - 1);
    const float* xb = x + (size_t)b * 64 * NNODES + nl0;

    if (blockIdx.x == 0) {                  // zpos table (was aux_k)
        for (int idx = t; idx < KE * 64; idx += 128) {
            int k = idx >> 6, h = idx & 63;
            int kk = k + (k >= 12 ? 1 : 0);
            int q5 = (kk * 52) >> 8;
            int dy = q5 - 2, dx = kk - 5 * q5 - 2;
            zpos[idx] = W1[h * 130 + 128] * (dx * 0.5f)
                      + W1[h * 130 + 129] * (dy * 0.5f);
        }
    }

    #pragma unroll
    for (int r = 0; r < 16; ++r) {
        int idx = r * 128 + t;
        int c = idx >> 5, j4 = idx & 31;
        float4 v = *(const float4*)(xb + (size_t)c * NNODES + j4 * 4);
        *(float4*)&xt[c][j4 * 4] = v;
    }
    #pragma unroll
    for (int r = 0; r < 32; ++r) {
        int idx = r * 128 + t;
        int c = idx >> 6, h = idx & 63;
        float v = (mat == 0) ? W1[h * 130 + c]
                : (mat == 1) ? W1[h * 130 + 64 + c]
                             : Wm[h * 64 + c];
        (&wl[0][0])[idx] = v;
    }
    __syncthreads();

    const int i = t >> 4;   // h-octet
    const int j = t & 15;   // node-group

    float acc[8][8];
    #pragma unroll
    for (int a = 0; a < 8; ++a)
        #pragma unroll
        for (int bb = 0; bb < 8; ++bb) acc[a][bb] = 0.f;

    #pragma unroll 4
    for (int c = 0; c < 64; ++c) {
        float4 w0 = *(const float4*)&wl[c][i * 8];
        float4 w1 = *(const float4*)&wl[c][i * 8 + 4];
        float4 x0 = *(const float4*)&xt[c][j * 8];
        float4 x1 = *(const float4*)&xt[c][j * 8 + 4];
        float wv[8] = {w0.x, w0.y, w0.z, w0.w, w1.x, w1.y, w1.z, w1.w};
        float xv[8] = {x0.x, x0.y, x0.z, x0.w, x1.x, x1.y, x1.z, x1.w};
        #pragma unroll
        for (int a = 0; a < 8; ++a)
            #pragma unroll
            for (int bb = 0; bb < 8; ++bb)
                acc[a][bb] = fmaf(wv[a], xv[bb], acc[a][bb]);
    }

    #pragma unroll
    for (int a = 0; a < 8; ++a) {
        float bv = (mat == 0) ? b1[i * 8 + a] : (mat == 2) ? bm[i * 8 + a] : 0.f;
        #pragma unroll
        for (int bb = 0; bb < 8; ++bb) {
            float v = acc[a][bb] + bv;
            acc[a][bb] = (mat == 2) ? fmaxf(v, 0.f) : v;
        }
    }

    float* dst = (mat == 0) ? zsrc : (mat == 1) ? ztgt : msg;
    #pragma unroll
    for (int nn = 0; nn < 8; ++nn) {
        float* o = dst + (size_t)(n0 + j * 8 + nn) * 64 + i * 8;
        *(float4*)o       = make_float4(acc[0][nn], acc[1][nn], acc[2][nn], acc[3][nn]);
        *(float4*)(o + 4) = make_float4(acc[4][nn], acc[5][nn], acc[6][nn], acc[7][nn]);
    }
}

// ---------------------------------------------------------------------------
// B: scorer. Exact 3-way-split bf16 MFMA. W2 frags built in LDS (cheap
//    materialization point) then hoisted ONCE into 12 register fragments —
//    loop body has zero fragment LDS reads. zpos staged in LDS.
// ---------------------------------------------------------------------------
__global__ __launch_bounds__(256, 3) void score_k(
    const float* __restrict__ zsrc, const float* __restrict__ ztgt,
    const float* __restrict__ zpos, const float* __restrict__ W2,
    const float* __restrict__ b2, const float* __restrict__ W3,
    const float* __restrict__ b3, float* __restrict__ scores)
{
    __shared__ fragcast fraglds[64 * 13];   // 13 KB, lane-major stride 13
    __shared__ float zpl[24 * 68];          // 6.5 KB, padded rows

    const int t = threadIdx.x;
    const int l = t & 63;
    const int lcol = l & 15;
    const int lgrp = l >> 4;
    const int w = t >> 6;
    const int wave = blockIdx.x * 4 + w;    // 8192 waves x 4 nodes

    // stage zpos (coalesced)
    #pragma unroll
    for (int r = 0; r < 6; ++r) {
        int idx = r * 256 + t;
        zpl[(idx >> 6) * 68 + (idx & 63)] = zpos[idx];
    }
    // W2 fragments: wave w builds quadrant (jt = w>>1, kt = w&1)
    {
        const int jt = w >> 1, kt = w & 1;
        fragcast fh, fl, fl2;
        const float* wr = W2 + (size_t)(jt * 16 + lcol) * 64 + kt * 32 + lgrp * 8;
        #pragma unroll
        for (int d = 0; d < 4; ++d) {
            unsigned h0, l0, m0, h1, l1, m1;
            split3(wr[2 * d],     h0, l0, m0);
            split3(wr[2 * d + 1], h1, l1, m1);
            fh.u[d]  = pack_hi16(h0, h1);
            fl.u[d]  = pack_hi16(l0, l1);
            fl2.u[d] = pack_hi16(m0, m1);
        }
        fraglds[l * 13 + 0 + jt * 2 + kt] = fh;
        fraglds[l * 13 + 4 + jt * 2 + kt] = fl;
        fraglds[l * 13 + 8 + jt * 2 + kt] = fl2;
    }
    __syncthreads();

    // hoist the 12 loop-invariant fragments into registers (48 VGPR)
    bf16x8 F[12];
    {
        const fragcast* fb = &fraglds[l * 13];
        #pragma unroll
        for (int i = 0; i < 12; ++i) F[i] = fb[i].b;
    }

    const f32x4 b2l0 = *(const f32x4*)(b2 + lgrp * 4);
    const f32x4 b2l1 = *(const f32x4*)(b2 + 16 + lgrp * 4);
    const f32x4 w3l0 = *(const f32x4*)(W3 + lgrp * 4);
    const f32x4 w3l1 = *(const f32x4*)(W3 + 16 + lgrp * 4);
    const float b3s = b3[0];

    #pragma unroll 1
    for (int p = 0; p < 2; ++p) {
        const int node0 = wave * 4 + p * 2;

        #pragma unroll
        for (int Mt = 0; Mt < 3; ++Mt) {
            const int ke = Mt * 16 + lcol;
            const int nsel = (ke >= 24) ? 1 : 0;
            const int node = node0 + nsel;
            const int k = ke - 24 * nsel;
            const int bb = node >> 14;
            const int nl = node & (NNODES - 1);
            const int yy = nl >> 7, xx = nl & 127;
            const int kk = k + (k >= 12 ? 1 : 0);
            const int q5 = (kk * 52) >> 8;
            const int dy = q5 - 2, dx = kk - 5 * q5 - 2;
            const int ny = min(max(yy + dy, 0), 127);
            const int nx = min(max(xx + dx, 0), 127);
            const int nbn = (bb << 14) + (ny << 7) + nx;

            const float* zs = zsrc + (size_t)node * 64 + lgrp * 8;
            const float* zt = ztgt + (size_t)nbn * 64 + lgrp * 8;
            const float* zp = &zpl[k * 68 + lgrp * 8];

            f32x4 ac0A = {0.f,0.f,0.f,0.f}, ac0B = {0.f,0.f,0.f,0.f};
            f32x4 ac1A = {0.f,0.f,0.f,0.f}, ac1B = {0.f,0.f,0.f,0.f};

            #pragma unroll
            for (int kt = 0; kt < 2; ++kt) {
                const int o = kt * 32;
                float4 a0 = *(const float4*)(zs + o);
                float4 a1 = *(const float4*)(zs + o + 4);
                float4 t0 = *(const float4*)(zt + o);
                float4 t1 = *(const float4*)(zt + o + 4);
                float4 p0 = *(const float4*)(zp + o);
                float4 p1 = *(const float4*)(zp + o + 4);
                float v[8];
                v[0] = fmaxf(a0.x + t0.x + p0.x, 0.f);
                v[1] = fmaxf(a0.y + t0.y + p0.y, 0.f);
                v[2] = fmaxf(a0.z + t0.z + p0.z, 0.f);
                v[3] = fmaxf(a0.w + t0.w + p0.w, 0.f);
                v[4] = fmaxf(a1.x + t1.x + p1.x, 0.f);
                v[5] = fmaxf(a1.y + t1.y + p1.y, 0.f);
                v[6] = fmaxf(a1.z + t1.z + p1.z, 0.f);
                v[7] = fmaxf(a1.w + t1.w + p1.w, 0.f);

                fragcast Bh, Bl, Bl2;
                #pragma unroll
                for (int d = 0; d < 4; ++d) {
                    unsigned h0, l0, m0, h1, l1, m1;
                    split3(v[2 * d],     h0, l0, m0);
                    split3(v[2 * d + 1], h1, l1, m1);
                    Bh.u[d]  = pack_hi16(h0, h1);
                    Bl.u[d]  = pack_hi16(l0, l1);
                    Bl2.u[d] = pack_hi16(m0, m1);
                }

                ac0A = __builtin_amdgcn_mfma_f32_16x16x32_bf16(F[0 + kt],  Bh.b,  ac0A, 0, 0, 0);
                ac1A = __builtin_amdgcn_mfma_f32_16x16x32_bf16(F[2 + kt],  Bh.b,  ac1A, 0, 0, 0);
                ac0B = __builtin_amdgcn_mfma_f32_16x16x32_bf16(F[4 + kt],  Bh.b,  ac0B, 0, 0, 0);
                ac1B = __builtin_amdgcn_mfma_f32_16x16x32_bf16(F[6 + kt],  Bh.b,  ac1B, 0, 0, 0);
                ac0A = __builtin_amdgcn_mfma_f32_16x16x32_bf16(F[8 + kt],  Bh.b,  ac0A, 0, 0, 0);
                ac1A = __builtin_amdgcn_mfma_f32_16x16x32_bf16(F[10 + kt], Bh.b,  ac1A, 0, 0, 0);
                ac0B = __builtin_amdgcn_mfma_f32_16x16x32_bf16(F[0 + kt],  Bl.b,  ac0B, 0, 0, 0);
                ac1B = __builtin_amdgcn_mfma_f32_16x16x32_bf16(F[2 + kt],  Bl.b,  ac1B, 0, 0, 0);
                ac0A = __builtin_amdgcn_mfma_f32_16x16x32_bf16(F[4 + kt],  Bl.b,  ac0A, 0, 0, 0);
                ac1A = __builtin_amdgcn_mfma_f32_16x16x32_bf16(F[6 + kt],  Bl.b,  ac1A, 0, 0, 0);
                ac0B = __builtin_amdgcn_mfma_f32_16x16x32_bf16(F[0 + kt],  Bl2.b, ac0B, 0, 0, 0);
                ac1B = __builtin_amdgcn_mfma_f32_16x16x32_bf16(F[2 + kt],  Bl2.b, ac1B, 0, 0, 0);
            }

            const f32x4 s0 = ac0A + ac0B;
            const f32x4 s1 = ac1A + ac1B;
            float sacc = 0.f;
            #pragma unroll
            for (int q = 0; q < 4; ++q) {
                sacc = fmaf(fmaxf(s0[q] + b2l0[q], 0.f), w3l0[q], sacc);
                sacc = fmaf(fmaxf(s1[q] + b2l1[q], 0.f), w3l1[q], sacc);
            }
            sacc += __shfl_xor(sacc, 16);
            sacc += __shfl_xor(sacc, 32);
            float sig = 1.f / (1.f + expf(-(sacc + b3s)));
            if (l < 16)
                scores[(size_t)node0 * 24 + Mt * 16 + l] = sig;
        }
    }
}

// ---------------------------------------------------------------------------
// C: per-node rank/mask/weights + weighted msg aggregation + Wo + residual.
// ---------------------------------------------------------------------------
__global__ __launch_bounds__(256) void agg_k(
    const float* __restrict__ x, const float* __restrict__ scores,
    const float* __restrict__ msg, const float* __restrict__ Wo,
    const float* __restrict__ bo, const float* __restrict__ thrp,
    float* __restrict__ out)
{
    __shared__ float sc[768];
    __shared__ float wl[768];
    __shared__ float sumw[32];
    __shared__ float aggL[32][64];
    __shared__ float ot[64][33];

    const int t = threadIdx.x;
    const int n0 = blockIdx.x * 32;
    const int b = n0 >> 14;
    const int nl0 = n0 & (NNODES - 1);
    const float thr_v = 1.f / (1.f + expf(-thrp[0]));

    #pragma unroll
    for (int rep = 0; rep < 3; ++rep)
        sc[rep * 256 + t] = scores[(size_t)n0 * 24 + rep * 256 + t];
    __syncthreads();

    #pragma unroll
    for (int rep = 0; rep < 3; ++rep) {
        int e = rep * 256 + t;
        int nl = (int)(((unsigned)(e >> 3) * 171u) >> 9);   // e/24 for e<768
        int k = e - nl * 24;
        float s_e = sc[e];
        int rank = 0, cnt = 0;
        #pragma unroll
        for (int j = 0; j < 24; ++j) {
            float sj = sc[nl * 24 + j];
            rank += (sj > s_e || (sj == s_e && j < k)) ? 1 : 0;
            cnt  += (sj >= thr_v) ? 1 : 0;
        }
        bool mask = (cnt > 8) ? (rank < 8)
                  : ((cnt < 3) ? (rank < 3) : (s_e >= thr_v));
        float keep = 1.f / (1.f + expf(-(s_e - thr_v) * 10.f));
        wl[e] = mask ? s_e * keep : 0.f;
    }
    __syncthreads();

    if (t < 32) {
        float s = 0.f;
        #pragma unroll
        for (int k = 0; k < 24; ++k) s += wl[t * 24 + k];
        sumw[t] = s + 1e-6f;
    }
    __syncthreads();

    const int lane = t & 63;
    const int g4 = t >> 6;

    #pragma unroll
    for (int it = 0; it < 8; ++it) {
        int nl = g4 + it * 4;
        int nn = nl0 + nl;
        int yy = nn >> 7, xx = nn & 127;
        float acc = 0.f;
        #pragma unroll
        for (int k = 0; k < 24; ++k) {
            int kk = k + (k >= 12 ? 1 : 0);
            int q5 = (kk * 52) >> 8;
            int dy = q5 - 2, dx = kk - 5 * q5 - 2;
            int ny = min(max(yy + dy, 0), 127);
            int nx = min(max(xx + dx, 0), 127);
            int nb = (b << 14) + (ny << 7) + nx;
            acc = fmaf(wl[nl * 24 + k], msg[(size_t)nb * 64 + lane], acc);
        }
        aggL[nl][lane] = acc / sumw[nl];
    }

    float4 wo[16];
    #pragma unroll
    for (int c4 = 0; c4 < 16; ++c4) wo[c4] = ((const float4*)Wo)[lane * 16 + c4];
    __syncthreads();

    #pragma unroll
    for (int it = 0; it < 8; ++it) {
        int nl = g4 + it * 4;
        const float4* ar = (const float4*)aggL[nl];
        float a0 = 0.f, a1 = 0.f, a2 = 0.f, a3 = 0.f;
        #pragma unroll
        for (int c4 = 0; c4 < 16; ++c4) {
            float4 wv = wo[c4];
            float4 av = ar[c4];
            a0 = fmaf(av.x, wv.x, a0);
            a1 = fmaf(av.y, wv.y, a1);
            a2 = fmaf(av.z, wv.z, a2);
            a3 = fmaf(av.w, wv.w, a3);
        }
        float v = (a0 + a1) + (a2 + a3) + bo[lane]
                + x[(size_t)b * 64 * NNODES + (size_t)lane * NNODES + nl0 + nl];
        ot[lane][nl] = v;
    }
    __syncthreads();

    #pragma unroll
    for (int rep = 0; rep < 2; ++rep) {
        int idx = rep * 256 + t;
        int o = idx >> 3, p = idx & 7;
        float4 v = make_float4(ot[o][4 * p + 0], ot[o][4 * p + 1],
                               ot[o][4 * p + 2], ot[o][4 * p + 3]);
        *(float4*)(out + (size_t)b * 64 * NNODES + (size_t)o * NNODES + nl0 + 4 * p) = v;
    }
}

// ---------------------------------------------------------------------------
extern "C" void kernel_launch(void* const* d_in, const int* in_sizes, int n_in,
                              void* d_out, int out_size, void* d_ws, size_t ws_size,
                              hipStream_t stream)
{
    const float* x   = (const float*)d_in[0];
    const float* W1  = (const float*)d_in[1];
    const float* b1  = (const float*)d_in[2];
    const float* W2  = (const float*)d_in[3];
    const float* b2  = (const float*)d_in[4];
    const float* W3  = (const float*)d_in[5];
    const float* b3  = (const float*)d_in[6];
    const float* thr = (const float*)d_in[7];
    const float* Wm  = (const float*)d_in[8];
    const float* bm  = (const float*)d_in[9];
    const float* Wo  = (const float*)d_in[10];
    const float* bo  = (const float*)d_in[11];
    float* out = (float*)d_out;
    float* ws  = (float*)d_ws;

    // ws layout (floats): zsrc[2M] ztgt[2M] msg[2M] scores[768K] zpos[1536]
    float* zsrc   = ws;
    float* ztgt   = ws + 2097152;
    float* msg    = ws + 4194304;
    float* scores = ws + 6291456;
    float* zpos   = ws + 7077888;

    hipLaunchKernelGGL(precompute_k, dim3(768), dim3(128), 0, stream,
                       x, W1, Wm, b1, bm, zsrc, ztgt, msg, zpos);
    hipLaunchKernelGGL(score_k, dim3(2048), dim3(256), 0, stream,
                       zsrc, ztgt, zpos, W2, b2, W3, b3, scores);
    hipLaunchKernelGGL(agg_k, dim3(1024), dim3(256), 0, stream,
                       x, scores, msg, Wo, bo, thr, out);
}